// Round 10
// baseline (17102.261 us; speedup 1.0000x reference)
//
#include <hip/hip_runtime.h>
#include <hip/hip_fp16.h>

#define TLEN 16384
#define HD 128

typedef _Float16 half2t __attribute__((ext_vector_type(2)));

__device__ __forceinline__ half2t u2h(unsigned int u) {
    union { unsigned int u; half2t h; } c; c.u = u; return c.h;
}
__device__ __forceinline__ unsigned short f2h_bits(float f) {
    union { _Float16 h; unsigned short s; } c; c.h = (_Float16)f; return c.s;
}
__device__ __forceinline__ half2t mkh2(float a, float b) {
    half2t h; h.x = (_Float16)a; h.y = (_Float16)b; return h;
}
// DPP cross-lane (VALU pipe, no LDS): quad_perm xor1=0xB1, xor2=0x4E;
// row_half_mirror (0x141) swaps lanes within each 8-lane half-row — after
// xor1+xor2 all 4 lanes of a quad are equal, so the mirror completes an
// 8-lane allreduce with one more level.
#define DPP_XOR1(x) __int_as_float(__builtin_amdgcn_update_dpp(0, __float_as_int(x), 0xB1, 0xF, 0xF, true))
#define DPP_XOR2(x) __int_as_float(__builtin_amdgcn_update_dpp(0, __float_as_int(x), 0x4E, 0xF, 0xF, true))
#define DPP_HMIR(x) __int_as_float(__builtin_amdgcn_update_dpp(0, __float_as_int(x), 0x141, 0xF, 0xF, true))

// ---------------------------------------------------------------------------
// Sequential GRU scan: 4 independent chains (channel-major — the reference's
// stack().transpose(0,2,1) makes "batch"=channel, "feature"=orig batch row).
// One block per chain, 1024 threads = 16 waves.
//
// R10: OCT-PER-K.  Thread (k=tid>>3, ln=tid&7) owns all 6 gate rows
// {k,128+k,256+k} x {Whh,Wih}, cols 16ln..16ln+15, as 48 packed-f16
// registers (R7/R8-proven resident; R9's 96-reg layout spilled at the
// compiler's hard 128-VGPR cap and cost ~800 cyc/step of spill VALU).
// Per step: 2 multicast ds_read_b128 of h, 48 v_dot2 (!ux) or 24+x-path
// (ux), 3-level all-DPP oct reduction, gates in-register (biases folded
// into acc init as bias/8), lane0 writes double-buffered h. ONE barrier.
// ---------------------------------------------------------------------------
__global__
__attribute__((amdgpu_flat_work_group_size(1024, 1024), amdgpu_waves_per_eu(4, 4)))
void gru_kernel(
    const float* __restrict__ px,
    const float* __restrict__ py,
    const float* __restrict__ vx,
    const float* __restrict__ vy,
    const float* __restrict__ Wemb,   // [128,4]
    const float* __restrict__ bemb,   // [128]
    const float* __restrict__ Wih,    // [384,128]
    const float* __restrict__ Whh,    // [384,128]
    const float* __restrict__ bih,    // [384]
    const float* __restrict__ bhh,    // [384]
    const int*   __restrict__ step_mask, // [16384]
    const int*   __restrict__ ctxp,      // [1]
    unsigned short* __restrict__ hs)     // [4*16384*128] f16-bits staging
{
    const int bb  = blockIdx.x;   // chain == channel
    const float* xsrc = (bb == 0) ? px : (bb == 1) ? py : (bb == 2) ? vx : vy;
    const int tid = threadIdx.x;
    const int k   = tid >> 3;     // h-index 0..127 (one oct each)
    const int ln  = tid & 7;      // col-block (16 cols)

    __shared__ alignas(16) _Float16 h2[2][HD];           // double-buffered h
    __shared__ alignas(16) unsigned short hring[32][HD]; // 32-slot f16 history
    __shared__ float xbuf[256 * 4];
    __shared__ int   uxbuf[256];
    __shared__ float WembL[HD * 4];
    __shared__ float bembL[HD];

    // ---- weights: 6 rows x 8 packed-f16 = 48 named registers ----
#define DECLROW(r) half2t w##r##_0, w##r##_1, w##r##_2, w##r##_3, \
                          w##r##_4, w##r##_5, w##r##_6, w##r##_7;
    DECLROW(0) DECLROW(1) DECLROW(2) DECLROW(3) DECLROW(4) DECLROW(5)
#undef DECLROW
#define LOADROW(r, PTR) { const float* rp = (PTR) + (ln << 4); \
        const float4 f0 = *(const float4*)(rp+ 0), f1 = *(const float4*)(rp+ 4); \
        const float4 f2 = *(const float4*)(rp+ 8), f3 = *(const float4*)(rp+12); \
        w##r##_0 = mkh2(f0.x,f0.y); w##r##_1 = mkh2(f0.z,f0.w); \
        w##r##_2 = mkh2(f1.x,f1.y); w##r##_3 = mkh2(f1.z,f1.w); \
        w##r##_4 = mkh2(f2.x,f2.y); w##r##_5 = mkh2(f2.z,f2.w); \
        w##r##_6 = mkh2(f3.x,f3.y); w##r##_7 = mkh2(f3.z,f3.w); }
    LOADROW(0, Whh + (size_t)(      k) * 128)
    LOADROW(1, Whh + (size_t)(128 + k) * 128)
    LOADROW(2, Whh + (size_t)(256 + k) * 128)
    LOADROW(3, Wih + (size_t)(      k) * 128)
    LOADROW(4, Wih + (size_t)(128 + k) * 128)
    LOADROW(5, Wih + (size_t)(256 + k) * 128)
#undef LOADROW

    // biases, pre-scaled by 1/8 so the 8-lane allreduce restores them
    const float b8_0 = bhh[      k] * 0.125f;
    const float b8_1 = bhh[128 + k] * 0.125f;
    const float b8_2 = bhh[256 + k] * 0.125f;
    const float b8_3 = bih[      k] * 0.125f;
    const float b8_4 = bih[128 + k] * 0.125f;
    const float b8_5 = bih[256 + k] * 0.125f;

    if (tid < 512) WembL[tid] = Wemb[tid];
    if (tid < 128) bembL[tid] = bemb[tid];
    if (tid < 128) h2[0][tid] = (_Float16)0.f;
    __syncthreads();

    // ---- per-thread embed fold (redundant across the oct; init-only):
    // Wc[row] (4-wide) and bc[row] = Wc·bemb + bih[row], rows {k,128+k,256+k}
    float4 wcr = {0,0,0,0}, wcz = {0,0,0,0}, wcn = {0,0,0,0};
    float bcr = bih[k], bcz = bih[128 + k], bcn = bih[256 + k];
    {
        const float* r0 = Wih + (size_t)(      k) * 128;
        const float* r1 = Wih + (size_t)(128 + k) * 128;
        const float* r2 = Wih + (size_t)(256 + k) * 128;
        for (int j = 0; j < 128; ++j) {
            const float4 e = *(const float4*)&WembL[j * 4];
            const float eb = bembL[j];
            const float a = r0[j], b = r1[j], c = r2[j];
            wcr.x = fmaf(a, e.x, wcr.x); wcr.y = fmaf(a, e.y, wcr.y);
            wcr.z = fmaf(a, e.z, wcr.z); wcr.w = fmaf(a, e.w, wcr.w);
            bcr   = fmaf(a, eb,  bcr);
            wcz.x = fmaf(b, e.x, wcz.x); wcz.y = fmaf(b, e.y, wcz.y);
            wcz.z = fmaf(b, e.z, wcz.z); wcz.w = fmaf(b, e.w, wcz.w);
            bcz   = fmaf(b, eb,  bcz);
            wcn.x = fmaf(c, e.x, wcn.x); wcn.y = fmaf(c, e.y, wcn.y);
            wcn.z = fmaf(c, e.z, wcn.z); wcn.w = fmaf(c, e.w, wcn.w);
            bcn   = fmaf(c, eb,  bcn);
        }
    }
    const int ctxm = (ctxp[0] < 1) ? 1 : ctxp[0];
    float hold = 0.f;   // this oct's h[k], kept redundantly in all 8 lanes

#define DOT8(r, acc, binit) { float a = (binit); \
        a = __builtin_amdgcn_fdot2(w##r##_0, hp0, a, false); \
        a = __builtin_amdgcn_fdot2(w##r##_1, hp1, a, false); \
        a = __builtin_amdgcn_fdot2(w##r##_2, hp2, a, false); \
        a = __builtin_amdgcn_fdot2(w##r##_3, hp3, a, false); \
        a = __builtin_amdgcn_fdot2(w##r##_4, hp4, a, false); \
        a = __builtin_amdgcn_fdot2(w##r##_5, hp5, a, false); \
        a = __builtin_amdgcn_fdot2(w##r##_6, hp6, a, false); \
        a = __builtin_amdgcn_fdot2(w##r##_7, hp7, a, false); \
        acc = a; }
#define QRED8(acc) { const float t1_ = acc + DPP_XOR1(acc); \
                     const float t2_ = t1_ + DPP_XOR2(t1_); \
                     acc = t2_ + DPP_HMIR(t2_); }

    for (int t0 = 0; t0 < TLEN; t0 += 256) {
        if (tid < 256) {
            const int gt = t0 + tid;
            xbuf[tid*4+0] = xsrc[0*TLEN + gt];
            xbuf[tid*4+1] = xsrc[1*TLEN + gt];
            xbuf[tid*4+2] = xsrc[2*TLEN + gt];
            xbuf[tid*4+3] = xsrc[3*TLEN + gt];
            uxbuf[tid] = ((gt < ctxm) || (step_mask[gt] == 0)) ? 1 : 0;
        }
        __syncthreads();
        for (int tt = 0; tt < 256; ++tt) {
            const int gt = t0 + tt;
            // flush completed 16-step group (disjoint ring half); issued at
            // step top so the store drain overlaps a full compute step.
            if ((gt & 15) == 1 && gt > 16 && tid >= 512 && tid < 768) {
                const int u  = tid - 512;
                const int G  = (gt >> 4) - 1;
                const int sl = u >> 4, g = u & 15;
                const int slot  = ((G & 1) << 4) + sl;
                const int gstep = (G << 4) + sl;
                *(uint4*)&hs[((size_t)(bb * TLEN + gstep) << 7) + (g << 3)] =
                    *(const uint4*)&hring[slot][g << 3];
            }
            const int ux = __builtin_amdgcn_readfirstlane(uxbuf[tt]);
            const uint4* hq = (const uint4*)h2[gt & 1];
            const uint4 q0 = hq[(ln << 1) + 0];
            const uint4 q1 = hq[(ln << 1) + 1];
            const half2t hp0 = u2h(q0.x), hp1 = u2h(q0.y),
                         hp2 = u2h(q0.z), hp3 = u2h(q0.w),
                         hp4 = u2h(q1.x), hp5 = u2h(q1.y),
                         hp6 = u2h(q1.z), hp7 = u2h(q1.w);
            float a0, a1, a2;
            DOT8(0, a0, b8_0) DOT8(1, a1, b8_1) DOT8(2, a2, b8_2)
            QRED8(a0) QRED8(a1) QRED8(a2)
            float gir, giz, gin;
            if (!ux) {
                float a3, a4, a5;
                DOT8(3, a3, b8_3) DOT8(4, a4, b8_4) DOT8(5, a5, b8_5)
                QRED8(a3) QRED8(a4) QRED8(a5)
                gir = a3; giz = a4; gin = a5;
            } else {
                const float4 xv = *(const float4*)&xbuf[tt * 4];
                gir = bcr; giz = bcz; gin = bcn;
                gir = fmaf(wcr.x, xv.x, gir); gir = fmaf(wcr.y, xv.y, gir);
                gir = fmaf(wcr.z, xv.z, gir); gir = fmaf(wcr.w, xv.w, gir);
                giz = fmaf(wcz.x, xv.x, giz); giz = fmaf(wcz.y, xv.y, giz);
                giz = fmaf(wcz.z, xv.z, giz); giz = fmaf(wcz.w, xv.w, giz);
                gin = fmaf(wcn.x, xv.x, gin); gin = fmaf(wcn.y, xv.y, gin);
                gin = fmaf(wcn.z, xv.z, gin); gin = fmaf(wcn.w, xv.w, gin);
            }
            // gates (PyTorch GRUCell: r,z,n); a0..a2 already include bhh
            const float r    = 1.f / (1.f + __expf(-(gir + a0)));
            const float z    = 1.f / (1.f + __expf(-(giz + a1)));
            const float npre = fmaf(r, a2, gin);
            const float e2   = __expf(2.f * npre);
            const float n    = 1.f - 2.f / (e2 + 1.f);   // tanh(npre)
            const float hnew = fmaf(z, hold - n, n);     // (1-z)n + z h
            hold = hnew;
            if (ln == 0) {
                h2[(gt + 1) & 1][k] = (_Float16)hnew;
                hring[gt & 31][k] = f2h_bits(hnew);
            }
            __syncthreads();
        }
    }
    // final flush: group 1023 (steps 16368..16383, slots 16..31)
    if (tid >= 512 && tid < 768) {
        const int u  = tid - 512;
        const int sl = u >> 4, g = u & 15;
        *(uint4*)&hs[((size_t)(bb * TLEN + 16368 + sl) << 7) + (g << 3)] =
            *(const uint4*)&hring[16 + sl][g << 3];
    }
#undef DOT8
#undef QRED8
}

// ---------------------------------------------------------------------------
// Head MLP over all 65536 hidden states: thread-per-row, weights uniform in
// LDS (broadcast reads), h in registers, y1 in padded LDS (stride 65).
// ---------------------------------------------------------------------------
__global__ __launch_bounds__(64) void head_kernel(
    const float*  __restrict__ W1,  // [64,128]
    const float*  __restrict__ b1,  // [64]
    const float*  __restrict__ W2,  // [64,64]
    const float*  __restrict__ b2,  // [64]
    const float*  __restrict__ W3,  // [2,64]
    const float*  __restrict__ b3,  // [2]
    const __half* __restrict__ hs,
    float*        __restrict__ out)
{
    __shared__ float W1L[64 * 128];
    __shared__ float W2L[64 * 64];
    __shared__ float W3L[2 * 64];
    __shared__ float b1L[64], b2L[64], b3L[2];
    __shared__ float y1L[64 * 65];   // per-thread row, stride 65 (bank pad)

    const int tid = threadIdx.x;
    {
        float4* dst1 = (float4*)W1L; const float4* src1 = (const float4*)W1;
        for (int i = tid; i < 2048; i += 64) dst1[i] = src1[i];
        float4* dst2 = (float4*)W2L; const float4* src2 = (const float4*)W2;
        for (int i = tid; i < 1024; i += 64) dst2[i] = src2[i];
        if (tid < 32) ((float4*)W3L)[tid] = ((const float4*)W3)[tid];
        b1L[tid] = b1[tid];
        b2L[tid] = b2[tid];
        if (tid < 2) b3L[tid] = b3[tid];
    }
    __syncthreads();

    const int row = blockIdx.x * 64 + tid;   // row = bb*16384 + t
    float h[128];
    {
        const uint4* hp = (const uint4*)(hs + (size_t)row * HD);
        #pragma unroll
        for (int c = 0; c < 16; ++c) {
            uint4 q = hp[c];
            const __half2* hh = (const __half2*)&q;
            #pragma unroll
            for (int d = 0; d < 4; ++d) {
                const float2 f = __half22float2(hh[d]);
                h[c*8 + d*2 + 0] = f.x;
                h[c*8 + d*2 + 1] = f.y;
            }
        }
    }
    // layer 1: y1 = elu(W1 h + b1)
    for (int l = 0; l < 64; ++l) {
        float a0 = b1L[l], a1 = 0.f;
        #pragma unroll
        for (int j = 0; j < 128; j += 4) {
            const float4 w = *(const float4*)&W1L[l*128 + j];
            a0 = fmaf(w.x, h[j+0], a0);
            a1 = fmaf(w.y, h[j+1], a1);
            a0 = fmaf(w.z, h[j+2], a0);
            a1 = fmaf(w.w, h[j+3], a1);
        }
        const float acc = a0 + a1;
        y1L[tid * 65 + l] = (acc > 0.f) ? acc : (__expf(acc) - 1.f);
    }
    // layer 2 + layer 3 fused: y3 += W3 * elu(W2 y1 + b2)
    float y30 = b3L[0], y31 = b3L[1];
    for (int l = 0; l < 64; ++l) {
        float a0 = b2L[l], a1 = 0.f;
        const int yb = tid * 65;
        #pragma unroll
        for (int j = 0; j < 64; j += 4) {
            const float4 w = *(const float4*)&W2L[l*64 + j];
            a0 = fmaf(w.x, y1L[yb + j+0], a0);
            a1 = fmaf(w.y, y1L[yb + j+1], a1);
            a0 = fmaf(w.z, y1L[yb + j+2], a0);
            a1 = fmaf(w.w, y1L[yb + j+3], a1);
        }
        const float acc = a0 + a1;
        const float v = (acc > 0.f) ? acc : (__expf(acc) - 1.f);
        y30 = fmaf(W3L[l],      v, y30);
        y31 = fmaf(W3L[64 + l], v, y31);
    }
    out[row]            = y30;
    out[4 * TLEN + row] = y31;
}

extern "C" void kernel_launch(void* const* d_in, const int* in_sizes, int n_in,
                              void* d_out, int out_size, void* d_ws, size_t ws_size,
                              hipStream_t stream) {
    const float* px   = (const float*)d_in[0];
    const float* py   = (const float*)d_in[1];
    const float* vx   = (const float*)d_in[2];
    const float* vy   = (const float*)d_in[3];
    const float* Wemb = (const float*)d_in[4];
    const float* bemb = (const float*)d_in[5];
    const float* Wih  = (const float*)d_in[6];
    const float* Whh  = (const float*)d_in[7];
    const float* bih  = (const float*)d_in[8];
    const float* bhh  = (const float*)d_in[9];
    const float* W1   = (const float*)d_in[10];
    const float* b1   = (const float*)d_in[11];
    const float* W2   = (const float*)d_in[12];
    const float* b2   = (const float*)d_in[13];
    const float* W3   = (const float*)d_in[14];
    const float* b3   = (const float*)d_in[15];
    const int* step_mask = (const int*)d_in[16];
    const int* ctx       = (const int*)d_in[17];
    unsigned short* hs = (unsigned short*)d_ws;  // 4*16384*128 f16-bits = 16.8 MB
    float* out = (float*)d_out;                  // f32, [2][4][16384] flat

    hipLaunchKernelGGL(gru_kernel, dim3(4), dim3(1024), 0, stream,
                       px, py, vx, vy, Wemb, bemb, Wih, Whh, bih, bhh,
                       step_mask, ctx, hs);
    hipLaunchKernelGGL(head_kernel, dim3(1024), dim3(64), 0, stream,
                       W1, b1, W2, b2, W3, b3, (const __half*)hs, out);
}

// Round 11
// 16310.918 us; speedup vs baseline: 1.0485x; 1.0485x over previous
//
#include <hip/hip_runtime.h>
#include <hip/hip_fp16.h>

#define TLEN 16384
#define HD 128
#define GGH (4 * 388)          // per-half gg stride (4 chains x 388-padded rows)

typedef _Float16 v8h __attribute__((ext_vector_type(8)));
typedef float    v4f __attribute__((ext_vector_type(4)));

union U4H8 { uint4 u; v8h h; };

__device__ __forceinline__ unsigned short f2h_bits(float f) {
    union { _Float16 h; unsigned short s; } c; c.h = (_Float16)f; return c.s;
}
__device__ __forceinline__ v8h cvt8(const float* p) {
    v8h r;
    #pragma unroll
    for (int i = 0; i < 8; ++i) r[i] = (_Float16)p[i];
    return r;
}

#define FORTI(X) X(0) X(1) X(2) X(3) X(4) X(5)

// ---------------------------------------------------------------------------
// R11: MFMA GRU scan, ALL 4 CHAINS IN ONE BLOCK (512 threads = 8 waves).
// The reference's stack().transpose(0,2,1) makes "batch"=channel ("chain"),
// "feature"=orig batch row.  Stacked G=[Whh(24 tiles);Wih(24 tiles)], tile =
// 16 gate-rows.  Wave w owns tiles 6w..6w+5; lane holds A-frag
// A[m=lane&15][k=(lane>>4)*8+j] per (tile,kt) => 24 v8h frags (96 regs,
// MFMA operands -> unified VGPR/AGPR file).  B-frag: lane = chain(lane&3)
// replicated over n, k=(lane>>4)*8+j from f16 h in LDS (4 ds_read_b128).
// D (col=lane&15=chain-replica, row=(lane>>4)*4+reg, m89-verified layout):
// lanes n<4 write float4 -> gg.  Phase B: thread per (chain,k) computes
// gates in f32 (h state f32 in-register), x-path via LDS Wc table on ux
// steps (waves 4-7 skip their MFMAs then).  2 barriers/step.
// R6-R10 lesson: VALU-dot designs are closed out by the allocator's 64/128
// reg grants; this moves the matvec to the idle matrix pipe (MfmaUtil=0
// all session) and cuts per-chain cost 4x by sharing MFMAs across chains.
// ---------------------------------------------------------------------------
__global__
__attribute__((amdgpu_flat_work_group_size(512, 512)))
void gru_kernel(
    const float* __restrict__ px,
    const float* __restrict__ py,
    const float* __restrict__ vx,
    const float* __restrict__ vy,
    const float* __restrict__ Wemb,   // [128,4]
    const float* __restrict__ bemb,   // [128]
    const float* __restrict__ Wih,    // [384,128]
    const float* __restrict__ Whh,    // [384,128]
    const float* __restrict__ bih,    // [384]
    const float* __restrict__ bhh,    // [384]
    const int*   __restrict__ step_mask, // [16384]
    const int*   __restrict__ ctxp,      // [1]
    unsigned short* __restrict__ hs)     // [4*16384*128] f16-bits staging
{
    const int tid  = threadIdx.x;
    const int w    = tid >> 6;      // wave 0..7 (0-3: Whh tiles, 4-7: Wih)
    const int lane = tid & 63;
    const int m    = lane & 15;     // A-frag row within tile
    const int q8   = (lane >> 4) * 8;   // A/B k-offset within 32-K frag
    const int nsel = lane & 15;     // D column
    const int qq4  = (lane >> 4) * 4;   // D row offset

    __shared__ alignas(16) float ggf[2 * GGH];          // raw matvec sums
    __shared__ alignas(16) _Float16 h2[2][4][HD];       // double-buffered h
    __shared__ alignas(16) unsigned short hring[32][512]; // [slot][c*128+k]
    __shared__ alignas(16) float xbuf[256][4][4];       // [t][chain][feat]
    __shared__ int   uxbuf[256];
    __shared__ float WembL[HD * 4];
    __shared__ float bembL[HD];
    __shared__ alignas(16) float Wc4[384][4];           // folded embed weights
    __shared__ float bcL[384];                          // Wc·bemb + bih
    __shared__ float biasHL[384], biasIL[384];

    // ---- A-fragments (once) ----
#define DECLA(ti) v8h a##ti##_0, a##ti##_1, a##ti##_2, a##ti##_3;
    FORTI(DECLA)
#undef DECLA
#define LOADA(ti) { \
        const int rt = 6 * w + (ti); const int rtl = (rt < 24) ? rt : rt - 24; \
        const float* rowp = ((rt < 24) ? Whh : Wih) + (size_t)(rtl * 16 + m) * 128 + q8; \
        a##ti##_0 = cvt8(rowp); a##ti##_1 = cvt8(rowp + 32); \
        a##ti##_2 = cvt8(rowp + 64); a##ti##_3 = cvt8(rowp + 96); }
    FORTI(LOADA)
#undef LOADA

    // ---- one-time LDS init ----
    if (tid < 512) WembL[tid] = Wemb[tid];
    if (tid < 128) bembL[tid] = bemb[tid];
    if (tid < 384) { biasHL[tid] = bhh[tid]; biasIL[tid] = bih[tid]; }
    if (tid < 128) { h2[0][tid >> 7][tid & 127] = (_Float16)0.f; }
    if (tid < 512) { h2[0][tid >> 7][tid & 127] = (_Float16)0.f; }
    __syncthreads();
    // folded embed: Wc[g] = Wih[g]·Wemb, bc[g] = Wih[g]·bemb + bih[g]
    if (tid < 384) {
        const float* wr = Wih + (size_t)tid * 128;
        float c0 = 0.f, c1 = 0.f, c2 = 0.f, c3 = 0.f, cb = bih[tid];
        #pragma unroll 4
        for (int j = 0; j < 128; ++j) {
            const float wv = wr[j];
            const float4 e = *(const float4*)&WembL[j * 4];
            c0 = fmaf(wv, e.x, c0); c1 = fmaf(wv, e.y, c1);
            c2 = fmaf(wv, e.z, c2); c3 = fmaf(wv, e.w, c3);
            cb = fmaf(wv, bembL[j], cb);
        }
        Wc4[tid][0] = c0; Wc4[tid][1] = c1; Wc4[tid][2] = c2; Wc4[tid][3] = c3;
        bcL[tid] = cb;
    }

    const int ctxm = (ctxp[0] < 1) ? 1 : ctxp[0];
    const int cB   = tid >> 7;    // phase-B chain
    const int kB   = tid & 127;   // phase-B h-index
    float hold = 0.f;             // f32 h state for (cB,kB)

    // prefetch pointer for this thread's chain slot
    const int cpre = tid & 3;
    const float* xsp = (cpre == 0) ? px : (cpre == 1) ? py : (cpre == 2) ? vx : vy;

    for (int t0 = 0; t0 < TLEN; t0 += 256) {
        // x/ux prefetch: thread i covers (t = i>>2, chain = i&3)
        for (int i = tid; i < 1024; i += 512) {
            const int t = i >> 2;
            const int gt = t0 + t;
            xbuf[t][cpre][0] = xsp[0 * TLEN + gt];
            xbuf[t][cpre][1] = xsp[1 * TLEN + gt];
            xbuf[t][cpre][2] = xsp[2 * TLEN + gt];
            xbuf[t][cpre][3] = xsp[3 * TLEN + gt];
        }
        if (tid < 256) {
            const int gt = t0 + tid;
            uxbuf[tid] = ((gt < ctxm) || (step_mask[gt] == 0)) ? 1 : 0;
        }
        __syncthreads();
        for (int tt = 0; tt < 256; ++tt) {
            const int gt = t0 + tt;
            // flush completed 16-step group (disjoint ring half) at step top
            if ((gt & 15) == 1 && gt > 16 && tid < 256) {
                const int G = (gt >> 4) - 1;
                #pragma unroll
                for (int j = 0; j < 4; ++j) {
                    const int u  = tid + (j << 8);
                    const int c  = u >> 8, sl = (u >> 4) & 15, g = u & 15;
                    ((uint4*)hs)[(size_t)(c * TLEN + G * 16 + sl) * 16 + g] =
                        ((const uint4*)hring)[(((G & 1) * 16 + sl) * 512 + c * 128 + g * 8) >> 3];
                }
            }
            const int ux = __builtin_amdgcn_readfirstlane(uxbuf[tt]);
            const int cur = gt & 1;
            if (!ux || w < 4) {
                // B-frags: lane = chain (lane&3), k = kt*32 + q8
                const uint4* hq = (const uint4*)h2[cur][lane & 3];
                U4H8 b0, b1, b2, b3;
                b0.u = hq[0 * 4 + (lane >> 4)];
                b1.u = hq[1 * 4 + (lane >> 4)];
                b2.u = hq[2 * 4 + (lane >> 4)];
                b3.u = hq[3 * 4 + (lane >> 4)];
#define TILE(ti) { \
                const int rt = 6 * w + (ti); const int rtl = (rt < 24) ? rt : rt - 24; \
                v4f acc = {0.f, 0.f, 0.f, 0.f}; \
                acc = __builtin_amdgcn_mfma_f32_16x16x32_f16(a##ti##_0, b0.h, acc, 0, 0, 0); \
                acc = __builtin_amdgcn_mfma_f32_16x16x32_f16(a##ti##_1, b1.h, acc, 0, 0, 0); \
                acc = __builtin_amdgcn_mfma_f32_16x16x32_f16(a##ti##_2, b2.h, acc, 0, 0, 0); \
                acc = __builtin_amdgcn_mfma_f32_16x16x32_f16(a##ti##_3, b3.h, acc, 0, 0, 0); \
                if (nsel < 4) \
                    *(v4f*)&ggf[((rt < 24) ? 0 : GGH) + nsel * 388 + rtl * 16 + qq4] = acc; }
                FORTI(TILE)
#undef TILE
            }
            __syncthreads();
            // ---- phase B: thread per (chain cB, index kB) ----
            {
                const float ghr = ggf[cB * 388 +       kB] + biasHL[      kB];
                const float ghz = ggf[cB * 388 + 128 + kB] + biasHL[128 + kB];
                const float ghn = ggf[cB * 388 + 256 + kB] + biasHL[256 + kB];
                float gir, giz, gin;
                if (ux) {
                    const float4 xv = *(const float4*)&xbuf[tt][cB][0];
                    const float4 wr = *(const float4*)&Wc4[      kB][0];
                    const float4 wz = *(const float4*)&Wc4[128 + kB][0];
                    const float4 wn = *(const float4*)&Wc4[256 + kB][0];
                    gir = bcL[      kB];
                    giz = bcL[128 + kB];
                    gin = bcL[256 + kB];
                    gir = fmaf(wr.x, xv.x, gir); gir = fmaf(wr.y, xv.y, gir);
                    gir = fmaf(wr.z, xv.z, gir); gir = fmaf(wr.w, xv.w, gir);
                    giz = fmaf(wz.x, xv.x, giz); giz = fmaf(wz.y, xv.y, giz);
                    giz = fmaf(wz.z, xv.z, giz); giz = fmaf(wz.w, xv.w, giz);
                    gin = fmaf(wn.x, xv.x, gin); gin = fmaf(wn.y, xv.y, gin);
                    gin = fmaf(wn.z, xv.z, gin); gin = fmaf(wn.w, xv.w, gin);
                } else {
                    gir = ggf[GGH + cB * 388 +       kB] + biasIL[      kB];
                    giz = ggf[GGH + cB * 388 + 128 + kB] + biasIL[128 + kB];
                    gin = ggf[GGH + cB * 388 + 256 + kB] + biasIL[256 + kB];
                }
                // PyTorch GRUCell order (r,z,n)
                const float r    = 1.f / (1.f + __expf(-(gir + ghr)));
                const float z    = 1.f / (1.f + __expf(-(giz + ghz)));
                const float npre = fmaf(r, ghn, gin);
                const float e2   = __expf(2.f * npre);
                const float n    = 1.f - 2.f / (e2 + 1.f);   // tanh(npre)
                const float hnew = fmaf(z, hold - n, n);     // (1-z)n + z h
                hold = hnew;
                h2[cur ^ 1][cB][kB] = (_Float16)hnew;
                hring[gt & 31][cB * 128 + kB] = f2h_bits(hnew);
            }
            __syncthreads();
        }
    }
    // final flush: group 1023 (steps 16368..16383, slots 16..31)
    if (tid < 256) {
        #pragma unroll
        for (int j = 0; j < 4; ++j) {
            const int u  = tid + (j << 8);
            const int c  = u >> 8, sl = (u >> 4) & 15, g = u & 15;
            ((uint4*)hs)[(size_t)(c * TLEN + 16368 + sl) * 16 + g] =
                ((const uint4*)hring)[((16 + sl) * 512 + c * 128 + g * 8) >> 3];
        }
    }
}

// ---------------------------------------------------------------------------
// Head MLP over all 65536 hidden states: thread-per-row, weights uniform in
// LDS (broadcast reads), h in registers, y1 in padded LDS (stride 65).
// ---------------------------------------------------------------------------
__global__ __launch_bounds__(64) void head_kernel(
    const float*  __restrict__ W1,  // [64,128]
    const float*  __restrict__ b1,  // [64]
    const float*  __restrict__ W2,  // [64,64]
    const float*  __restrict__ b2,  // [64]
    const float*  __restrict__ W3,  // [2,64]
    const float*  __restrict__ b3,  // [2]
    const __half* __restrict__ hs,
    float*        __restrict__ out)
{
    __shared__ float W1L[64 * 128];
    __shared__ float W2L[64 * 64];
    __shared__ float W3L[2 * 64];
    __shared__ float b1L[64], b2L[64], b3L[2];
    __shared__ float y1L[64 * 65];   // per-thread row, stride 65 (bank pad)

    const int tid = threadIdx.x;
    {
        float4* dst1 = (float4*)W1L; const float4* src1 = (const float4*)W1;
        for (int i = tid; i < 2048; i += 64) dst1[i] = src1[i];
        float4* dst2 = (float4*)W2L; const float4* src2 = (const float4*)W2;
        for (int i = tid; i < 1024; i += 64) dst2[i] = src2[i];
        if (tid < 32) ((float4*)W3L)[tid] = ((const float4*)W3)[tid];
        b1L[tid] = b1[tid];
        b2L[tid] = b2[tid];
        if (tid < 2) b3L[tid] = b3[tid];
    }
    __syncthreads();

    const int row = blockIdx.x * 64 + tid;   // row = c*16384 + t
    float h[128];
    {
        const uint4* hp = (const uint4*)(hs + (size_t)row * HD);
        #pragma unroll
        for (int c = 0; c < 16; ++c) {
            uint4 q = hp[c];
            const __half2* hh = (const __half2*)&q;
            #pragma unroll
            for (int d = 0; d < 4; ++d) {
                const float2 f = __half22float2(hh[d]);
                h[c*8 + d*2 + 0] = f.x;
                h[c*8 + d*2 + 1] = f.y;
            }
        }
    }
    // layer 1: y1 = elu(W1 h + b1)
    for (int l = 0; l < 64; ++l) {
        float a0 = b1L[l], a1 = 0.f;
        #pragma unroll
        for (int j = 0; j < 128; j += 4) {
            const float4 w = *(const float4*)&W1L[l*128 + j];
            a0 = fmaf(w.x, h[j+0], a0);
            a1 = fmaf(w.y, h[j+1], a1);
            a0 = fmaf(w.z, h[j+2], a0);
            a1 = fmaf(w.w, h[j+3], a1);
        }
        const float acc = a0 + a1;
        y1L[tid * 65 + l] = (acc > 0.f) ? acc : (__expf(acc) - 1.f);
    }
    // layer 2 + layer 3 fused: y3 += W3 * elu(W2 y1 + b2)
    float y30 = b3L[0], y31 = b3L[1];
    for (int l = 0; l < 64; ++l) {
        float a0 = b2L[l], a1 = 0.f;
        const int yb = tid * 65;
        #pragma unroll
        for (int j = 0; j < 64; j += 4) {
            const float4 w = *(const float4*)&W2L[l*64 + j];
            a0 = fmaf(w.x, y1L[yb + j+0], a0);
            a1 = fmaf(w.y, y1L[yb + j+1], a1);
            a0 = fmaf(w.z, y1L[yb + j+2], a0);
            a1 = fmaf(w.w, y1L[yb + j+3], a1);
        }
        const float acc = a0 + a1;
        const float v = (acc > 0.f) ? acc : (__expf(acc) - 1.f);
        y30 = fmaf(W3L[l],      v, y30);
        y31 = fmaf(W3L[64 + l], v, y31);
    }
    out[row]            = y30;
    out[4 * TLEN + row] = y31;
}

extern "C" void kernel_launch(void* const* d_in, const int* in_sizes, int n_in,
                              void* d_out, int out_size, void* d_ws, size_t ws_size,
                              hipStream_t stream) {
    const float* px   = (const float*)d_in[0];
    const float* py   = (const float*)d_in[1];
    const float* vx   = (const float*)d_in[2];
    const float* vy   = (const float*)d_in[3];
    const float* Wemb = (const float*)d_in[4];
    const float* bemb = (const float*)d_in[5];
    const float* Wih  = (const float*)d_in[6];
    const float* Whh  = (const float*)d_in[7];
    const float* bih  = (const float*)d_in[8];
    const float* bhh  = (const float*)d_in[9];
    const float* W1   = (const float*)d_in[10];
    const float* b1   = (const float*)d_in[11];
    const float* W2   = (const float*)d_in[12];
    const float* b2   = (const float*)d_in[13];
    const float* W3   = (const float*)d_in[14];
    const float* b3   = (const float*)d_in[15];
    const int* step_mask = (const int*)d_in[16];
    const int* ctx       = (const int*)d_in[17];
    unsigned short* hs = (unsigned short*)d_ws;  // 4*16384*128 f16-bits = 16.8 MB
    float* out = (float*)d_out;                  // f32, [2][4][16384] flat

    hipLaunchKernelGGL(gru_kernel, dim3(1), dim3(512), 0, stream,
                       px, py, vx, vy, Wemb, bemb, Wih, Whh, bih, bhh,
                       step_mask, ctx, hs);
    hipLaunchKernelGGL(head_kernel, dim3(1024), dim3(64), 0, stream,
                       W1, b1, W2, b2, W3, b3, (const __half*)hs, out);
}

// Round 12
// 11102.993 us; speedup vs baseline: 1.5403x; 1.4691x over previous
//
#include <hip/hip_runtime.h>
#include <hip/hip_fp16.h>

#define TLEN 16384
#define HD 128

typedef _Float16 v8h __attribute__((ext_vector_type(8)));
typedef float    v4f __attribute__((ext_vector_type(4)));

union U4H8 { uint4 u; v8h h; };

__device__ __forceinline__ v8h cvt8(const float* p) {
    v8h r;
    #pragma unroll
    for (int i = 0; i < 8; ++i) r[i] = (_Float16)p[i];
    return r;
}
__device__ __forceinline__ unsigned int packh2(float a, float b) {
    union { _Float16 h[2]; unsigned int u; } c;
    c.h[0] = (_Float16)a; c.h[1] = (_Float16)b; return c.u;
}
// compile-time-indexed component select (runtime g, no dynamic extract)
__device__ __forceinline__ float selg(v4f a, int g) {
    const float lo = (g & 1) ? a.y : a.x;
    const float hi = (g & 1) ? a.w : a.z;
    return (g & 2) ? hi : lo;
}
// pin a fragment into the AGPR half of the unified file: relieves the arch
// VGPR budget (allocator grants only ~128 at 8-wave blocks) AND is
// remat-proof (asm is opaque -> no per-step reload from global).
#define PINA(x) asm volatile("" : "+a"(x))

// ---------------------------------------------------------------------------
// R12: MFMA GRU scan, 4 chains in ONE block (512 thr, 8 waves), IN-REGISTER
// GATES, ONE barrier/step.
// Wave w owns gate-rows 16w..16w+15 for r,z,n x {Whh,Wih}: 6 tiles x 4
// K-frags = 24 A-frags (96 regs, pinned to AGPR).  B-frags: h (f16, padded
// c-stride 320B => conflict-free multicast).  Biases ride as MFMA C-init.
// D-lane (q=lane>>4, n=lane&15) holds all 6 preacts for chain c=n&3,
// rows 4q..4q+3; replica groups g=(lane>>2)&3 split the row work so all 64
// lanes compute ONE gate-triple and write ONE f16 (k = 16w+4q+g).
// ux steps: Wih MFMAs replaced by 3 Wc-MFMAs (Wc=Wih*Wemb folded, K=5 via
// x padded with 1.0 carrying the bemb fold) — B from xpad, zeroed on
// lanes q8!=0.  R11 verified every fragment-layout convention used here.
// ---------------------------------------------------------------------------
__global__
__attribute__((amdgpu_flat_work_group_size(512, 512)))
void gru_kernel(
    const float* __restrict__ px,
    const float* __restrict__ py,
    const float* __restrict__ vx,
    const float* __restrict__ vy,
    const float* __restrict__ Wemb,   // [128,4]
    const float* __restrict__ bemb,   // [128]
    const float* __restrict__ Wih,    // [384,128]
    const float* __restrict__ Whh,    // [384,128]
    const float* __restrict__ bih,    // [384]
    const float* __restrict__ bhh,    // [384]
    const int*   __restrict__ step_mask, // [16384]
    const int*   __restrict__ ctxp,      // [1]
    unsigned short* __restrict__ hs)     // [4*16384*128] f16-bits staging
{
    const int tid  = threadIdx.x;
    const int w    = tid >> 6;          // wave 0..7 -> k-range 16w..16w+15
    const int lane = tid & 63;
    const int m    = lane & 15;         // A-frag row within 16-row tile
    const int q8   = (lane >> 4) * 8;   // A/B k-offset within 32-K frag
    const int qq4  = (lane >> 4) * 4;   // D row-block
    const int cme  = lane & 3;          // my chain (D col & B chain)
    const int gme  = (lane >> 2) & 3;   // my row-within-block (replica split)
    const int kme  = 16 * w + qq4 + gme; // my h index

    __shared__ alignas(16) _Float16 h2L[2][4][160];      // padded c-stride
    __shared__ alignas(16) _Float16 hringL[32][4][136];  // padded history
    __shared__ alignas(16) uint4 xpadL[256][4];          // [x0..x3,1,0,0,0] f16
    __shared__ int   uxbuf[256];
    __shared__ float WembL[512];
    __shared__ float bembL[128];
    __shared__ alignas(16) float Wc4[384][4];
    __shared__ float bfoldL[384];                        // Wih·bemb (no bih)

    // ---- A-fragments: 6 tiles x 4 kfrags ----
    v8h ahr0, ahr1, ahr2, ahr3, ahz0, ahz1, ahz2, ahz3, ahn0, ahn1, ahn2, ahn3;
    v8h air0, air1, air2, air3, aiz0, aiz1, aiz2, aiz3, ain0, ain1, ain2, ain3;
    {
        const float* pr = Whh + (size_t)(      16 * w + m) * 128 + q8;
        const float* pz = Whh + (size_t)(128 + 16 * w + m) * 128 + q8;
        const float* pn = Whh + (size_t)(256 + 16 * w + m) * 128 + q8;
        ahr0 = cvt8(pr); ahr1 = cvt8(pr + 32); ahr2 = cvt8(pr + 64); ahr3 = cvt8(pr + 96);
        ahz0 = cvt8(pz); ahz1 = cvt8(pz + 32); ahz2 = cvt8(pz + 64); ahz3 = cvt8(pz + 96);
        ahn0 = cvt8(pn); ahn1 = cvt8(pn + 32); ahn2 = cvt8(pn + 64); ahn3 = cvt8(pn + 96);
        const float* qr = Wih + (size_t)(      16 * w + m) * 128 + q8;
        const float* qz = Wih + (size_t)(128 + 16 * w + m) * 128 + q8;
        const float* qn = Wih + (size_t)(256 + 16 * w + m) * 128 + q8;
        air0 = cvt8(qr); air1 = cvt8(qr + 32); air2 = cvt8(qr + 64); air3 = cvt8(qr + 96);
        aiz0 = cvt8(qz); aiz1 = cvt8(qz + 32); aiz2 = cvt8(qz + 64); aiz3 = cvt8(qz + 96);
        ain0 = cvt8(qn); ain1 = cvt8(qn + 32); ain2 = cvt8(qn + 64); ain3 = cvt8(qn + 96);
    }
    PINA(ahr0); PINA(ahr1); PINA(ahr2); PINA(ahr3);
    PINA(ahz0); PINA(ahz1); PINA(ahz2); PINA(ahz3);
    PINA(ahn0); PINA(ahn1); PINA(ahn2); PINA(ahn3);
    PINA(air0); PINA(air1); PINA(air2); PINA(air3);
    PINA(aiz0); PINA(aiz1); PINA(aiz2); PINA(aiz3);
    PINA(ain0); PINA(ain1); PINA(ain2); PINA(ain3);

    // ---- biases as MFMA C-initializers (D rows 4q..4q+3 of the tile) ----
    const int rB = 16 * w + qq4;
    const v4f bHR = { bhh[rB],       bhh[rB + 1],       bhh[rB + 2],       bhh[rB + 3] };
    const v4f bHZ = { bhh[128 + rB], bhh[128 + rB + 1], bhh[128 + rB + 2], bhh[128 + rB + 3] };
    const v4f bHN = { bhh[256 + rB], bhh[256 + rB + 1], bhh[256 + rB + 2], bhh[256 + rB + 3] };
    const v4f bIR = { bih[rB],       bih[rB + 1],       bih[rB + 2],       bih[rB + 3] };
    const v4f bIZ = { bih[128 + rB], bih[128 + rB + 1], bih[128 + rB + 2], bih[128 + rB + 3] };
    const v4f bIN = { bih[256 + rB], bih[256 + rB + 1], bih[256 + rB + 2], bih[256 + rB + 3] };

    if (tid < 512) WembL[tid] = Wemb[tid];
    if (tid < 128) bembL[tid] = bemb[tid];
    for (int i = tid; i < 2 * 4 * 160; i += 512) ((_Float16*)h2L)[i] = (_Float16)0.f;
    __syncthreads();
    // folded embed: Wc[g] = Wih[g]·Wemb, bfold[g] = Wih[g]·bemb  (NO bih)
    if (tid < 384) {
        const float* wr = Wih + (size_t)tid * 128;
        float c0 = 0.f, c1 = 0.f, c2 = 0.f, c3 = 0.f, cb = 0.f;
        #pragma unroll 4
        for (int j = 0; j < 128; ++j) {
            const float wv = wr[j];
            const float4 e = *(const float4*)&WembL[j * 4];
            c0 = fmaf(wv, e.x, c0); c1 = fmaf(wv, e.y, c1);
            c2 = fmaf(wv, e.z, c2); c3 = fmaf(wv, e.w, c3);
            cb = fmaf(wv, bembL[j], cb);
        }
        Wc4[tid][0] = c0; Wc4[tid][1] = c1; Wc4[tid][2] = c2; Wc4[tid][3] = c3;
        bfoldL[tid] = cb;
    }
    __syncthreads();
    // Wc A-frags: k=0..3 = Wc row, k=4 = bemb-fold, rest 0; lanes q8!=0 zero
    v8h wcr = {}, wcz = {}, wcn = {};
    if (lane < 16) {
        wcr[0] = (_Float16)Wc4[      16 * w + m][0]; wcr[1] = (_Float16)Wc4[      16 * w + m][1];
        wcr[2] = (_Float16)Wc4[      16 * w + m][2]; wcr[3] = (_Float16)Wc4[      16 * w + m][3];
        wcr[4] = (_Float16)bfoldL[      16 * w + m];
        wcz[0] = (_Float16)Wc4[128 + 16 * w + m][0]; wcz[1] = (_Float16)Wc4[128 + 16 * w + m][1];
        wcz[2] = (_Float16)Wc4[128 + 16 * w + m][2]; wcz[3] = (_Float16)Wc4[128 + 16 * w + m][3];
        wcz[4] = (_Float16)bfoldL[128 + 16 * w + m];
        wcn[0] = (_Float16)Wc4[256 + 16 * w + m][0]; wcn[1] = (_Float16)Wc4[256 + 16 * w + m][1];
        wcn[2] = (_Float16)Wc4[256 + 16 * w + m][2]; wcn[3] = (_Float16)Wc4[256 + 16 * w + m][3];
        wcn[4] = (_Float16)bfoldL[256 + 16 * w + m];
    }
    PINA(wcr); PINA(wcz); PINA(wcn);

    const int ctxm = (ctxp[0] < 1) ? 1 : ctxp[0];
    float hold1 = 0.f;                 // my (cme,kme) h state, f32

    for (int t0 = 0; t0 < TLEN; t0 += 256) {
        // prefetch x (f16-padded with 1.0 at k=4) + use_x flags
        for (int i = tid; i < 1024; i += 512) {
            const int t = i >> 2, c = i & 3;
            const int gt = t0 + t;
            const float* xa = (c == 0) ? px : (c == 1) ? py : (c == 2) ? vx : vy;
            uint4 u;
            u.x = packh2(xa[gt],            xa[TLEN + gt]);
            u.y = packh2(xa[2 * TLEN + gt], xa[3 * TLEN + gt]);
            u.z = packh2(1.f, 0.f);
            u.w = 0u;
            xpadL[t][c] = u;
        }
        if (tid < 256) {
            const int gt = t0 + tid;
            uxbuf[tid] = ((gt < ctxm) || (step_mask[gt] == 0)) ? 1 : 0;
        }
        __syncthreads();
        for (int tt = 0; tt < 256; ++tt) {
            const int gt = t0 + tt;
            // flush completed 16-step group (disjoint ring half) at step top
            if ((gt & 15) == 1 && gt > 16 && tid < 256) {
                const int G = (gt >> 4) - 1;
                #pragma unroll
                for (int j = 0; j < 4; ++j) {
                    const int u  = tid + (j << 8);
                    const int c  = u >> 8, sl = (u >> 4) & 15, g = u & 15;
                    ((uint4*)hs)[(size_t)(c * TLEN + (G << 4) + sl) * 16 + g] =
                        *(const uint4*)&hringL[((G & 1) << 4) + sl][c][g << 3];
                }
            }
            const int ux  = __builtin_amdgcn_readfirstlane(uxbuf[tt]);
            const int cur = gt & 1, nxt = cur ^ 1;
            // B-frags: conflict-free multicast (c-stride 320B)
            const uint4* hq = (const uint4*)&h2L[cur][cme][0];
            U4H8 b0, b1, b2, b3;
            b0.u = hq[ 0 + (lane >> 4)];
            b1.u = hq[ 4 + (lane >> 4)];
            b2.u = hq[ 8 + (lane >> 4)];
            b3.u = hq[12 + (lane >> 4)];
            v4f aHR = __builtin_amdgcn_mfma_f32_16x16x32_f16(ahr0, b0.h, bHR, 0, 0, 0);
            aHR     = __builtin_amdgcn_mfma_f32_16x16x32_f16(ahr1, b1.h, aHR, 0, 0, 0);
            aHR     = __builtin_amdgcn_mfma_f32_16x16x32_f16(ahr2, b2.h, aHR, 0, 0, 0);
            aHR     = __builtin_amdgcn_mfma_f32_16x16x32_f16(ahr3, b3.h, aHR, 0, 0, 0);
            v4f aHZ = __builtin_amdgcn_mfma_f32_16x16x32_f16(ahz0, b0.h, bHZ, 0, 0, 0);
            aHZ     = __builtin_amdgcn_mfma_f32_16x16x32_f16(ahz1, b1.h, aHZ, 0, 0, 0);
            aHZ     = __builtin_amdgcn_mfma_f32_16x16x32_f16(ahz2, b2.h, aHZ, 0, 0, 0);
            aHZ     = __builtin_amdgcn_mfma_f32_16x16x32_f16(ahz3, b3.h, aHZ, 0, 0, 0);
            v4f aHN = __builtin_amdgcn_mfma_f32_16x16x32_f16(ahn0, b0.h, bHN, 0, 0, 0);
            aHN     = __builtin_amdgcn_mfma_f32_16x16x32_f16(ahn1, b1.h, aHN, 0, 0, 0);
            aHN     = __builtin_amdgcn_mfma_f32_16x16x32_f16(ahn2, b2.h, aHN, 0, 0, 0);
            aHN     = __builtin_amdgcn_mfma_f32_16x16x32_f16(ahn3, b3.h, aHN, 0, 0, 0);
            v4f aIR, aIZ, aIN;
            if (!ux) {
                aIR = __builtin_amdgcn_mfma_f32_16x16x32_f16(air0, b0.h, bIR, 0, 0, 0);
                aIR = __builtin_amdgcn_mfma_f32_16x16x32_f16(air1, b1.h, aIR, 0, 0, 0);
                aIR = __builtin_amdgcn_mfma_f32_16x16x32_f16(air2, b2.h, aIR, 0, 0, 0);
                aIR = __builtin_amdgcn_mfma_f32_16x16x32_f16(air3, b3.h, aIR, 0, 0, 0);
                aIZ = __builtin_amdgcn_mfma_f32_16x16x32_f16(aiz0, b0.h, bIZ, 0, 0, 0);
                aIZ = __builtin_amdgcn_mfma_f32_16x16x32_f16(aiz1, b1.h, aIZ, 0, 0, 0);
                aIZ = __builtin_amdgcn_mfma_f32_16x16x32_f16(aiz2, b2.h, aIZ, 0, 0, 0);
                aIZ = __builtin_amdgcn_mfma_f32_16x16x32_f16(aiz3, b3.h, aIZ, 0, 0, 0);
                aIN = __builtin_amdgcn_mfma_f32_16x16x32_f16(ain0, b0.h, bIN, 0, 0, 0);
                aIN = __builtin_amdgcn_mfma_f32_16x16x32_f16(ain1, b1.h, aIN, 0, 0, 0);
                aIN = __builtin_amdgcn_mfma_f32_16x16x32_f16(ain2, b2.h, aIN, 0, 0, 0);
                aIN = __builtin_amdgcn_mfma_f32_16x16x32_f16(ain3, b3.h, aIN, 0, 0, 0);
            } else {
                U4H8 xb;
                xb.u = xpadL[tt][cme];
                if (lane >= 16) { xb.u.x = 0u; xb.u.y = 0u; xb.u.z = 0u; xb.u.w = 0u; }
                aIR = __builtin_amdgcn_mfma_f32_16x16x32_f16(wcr, xb.h, bIR, 0, 0, 0);
                aIZ = __builtin_amdgcn_mfma_f32_16x16x32_f16(wcz, xb.h, bIZ, 0, 0, 0);
                aIN = __builtin_amdgcn_mfma_f32_16x16x32_f16(wcn, xb.h, bIN, 0, 0, 0);
            }
            // gates, one (c,k) per lane (replica split) — all biases included
            const float gir = selg(aIR, gme), ghr = selg(aHR, gme);
            const float giz = selg(aIZ, gme), ghz = selg(aHZ, gme);
            const float gin = selg(aIN, gme), ghn = selg(aHN, gme);
            const float r    = 1.f / (1.f + __expf(-(gir + ghr)));
            const float z    = 1.f / (1.f + __expf(-(giz + ghz)));
            const float npre = fmaf(r, ghn, gin);
            const float e2   = __expf(2.f * npre);
            const float n    = 1.f - 2.f / (e2 + 1.f);       // tanh(npre)
            const float hnew = fmaf(z, hold1 - n, n);        // (1-z)n + z h
            hold1 = hnew;
            h2L[nxt][cme][kme]         = (_Float16)hnew;
            hringL[gt & 31][cme][kme]  = (_Float16)hnew;
            __syncthreads();
        }
    }
    // final flush: steps 16368..16383 (slots 16..31)
    if (tid < 256) {
        #pragma unroll
        for (int j = 0; j < 4; ++j) {
            const int u  = tid + (j << 8);
            const int c  = u >> 8, sl = (u >> 4) & 15, g = u & 15;
            ((uint4*)hs)[(size_t)(c * TLEN + 16368 + sl) * 16 + g] =
                *(const uint4*)&hringL[16 + sl][c][g << 3];
        }
    }
}

// ---------------------------------------------------------------------------
// Head MLP over all 65536 hidden states (unchanged).
// ---------------------------------------------------------------------------
__global__ __launch_bounds__(64) void head_kernel(
    const float*  __restrict__ W1,
    const float*  __restrict__ b1,
    const float*  __restrict__ W2,
    const float*  __restrict__ b2,
    const float*  __restrict__ W3,
    const float*  __restrict__ b3,
    const __half* __restrict__ hs,
    float*        __restrict__ out)
{
    __shared__ float W1L[64 * 128];
    __shared__ float W2L[64 * 64];
    __shared__ float W3L[2 * 64];
    __shared__ float b1L[64], b2L[64], b3L[2];
    __shared__ float y1L[64 * 65];

    const int tid = threadIdx.x;
    {
        float4* dst1 = (float4*)W1L; const float4* src1 = (const float4*)W1;
        for (int i = tid; i < 2048; i += 64) dst1[i] = src1[i];
        float4* dst2 = (float4*)W2L; const float4* src2 = (const float4*)W2;
        for (int i = tid; i < 1024; i += 64) dst2[i] = src2[i];
        if (tid < 32) ((float4*)W3L)[tid] = ((const float4*)W3)[tid];
        b1L[tid] = b1[tid];
        b2L[tid] = b2[tid];
        if (tid < 2) b3L[tid] = b3[tid];
    }
    __syncthreads();

    const int row = blockIdx.x * 64 + tid;
    float h[128];
    {
        const uint4* hp = (const uint4*)(hs + (size_t)row * HD);
        #pragma unroll
        for (int c = 0; c < 16; ++c) {
            uint4 q = hp[c];
            const __half2* hh = (const __half2*)&q;
            #pragma unroll
            for (int d = 0; d < 4; ++d) {
                const float2 f = __half22float2(hh[d]);
                h[c*8 + d*2 + 0] = f.x;
                h[c*8 + d*2 + 1] = f.y;
            }
        }
    }
    for (int l = 0; l < 64; ++l) {
        float a0 = b1L[l], a1 = 0.f;
        #pragma unroll
        for (int j = 0; j < 128; j += 4) {
            const float4 wv = *(const float4*)&W1L[l*128 + j];
            a0 = fmaf(wv.x, h[j+0], a0);
            a1 = fmaf(wv.y, h[j+1], a1);
            a0 = fmaf(wv.z, h[j+2], a0);
            a1 = fmaf(wv.w, h[j+3], a1);
        }
        const float acc = a0 + a1;
        y1L[tid * 65 + l] = (acc > 0.f) ? acc : (__expf(acc) - 1.f);
    }
    float y30 = b3L[0], y31 = b3L[1];
    for (int l = 0; l < 64; ++l) {
        float a0 = b2L[l], a1 = 0.f;
        const int yb = tid * 65;
        #pragma unroll
        for (int j = 0; j < 64; j += 4) {
            const float4 wv = *(const float4*)&W2L[l*64 + j];
            a0 = fmaf(wv.x, y1L[yb + j+0], a0);
            a1 = fmaf(wv.y, y1L[yb + j+1], a1);
            a0 = fmaf(wv.z, y1L[yb + j+2], a0);
            a1 = fmaf(wv.w, y1L[yb + j+3], a1);
        }
        const float acc = a0 + a1;
        const float v = (acc > 0.f) ? acc : (__expf(acc) - 1.f);
        y30 = fmaf(W3L[l],      v, y30);
        y31 = fmaf(W3L[64 + l], v, y31);
    }
    out[row]            = y30;
    out[4 * TLEN + row] = y31;
}

extern "C" void kernel_launch(void* const* d_in, const int* in_sizes, int n_in,
                              void* d_out, int out_size, void* d_ws, size_t ws_size,
                              hipStream_t stream) {
    const float* px   = (const float*)d_in[0];
    const float* py   = (const float*)d_in[1];
    const float* vx   = (const float*)d_in[2];
    const float* vy   = (const float*)d_in[3];
    const float* Wemb = (const float*)d_in[4];
    const float* bemb = (const float*)d_in[5];
    const float* Wih  = (const float*)d_in[6];
    const float* Whh  = (const float*)d_in[7];
    const float* bih  = (const float*)d_in[8];
    const float* bhh  = (const float*)d_in[9];
    const float* W1   = (const float*)d_in[10];
    const float* b1   = (const float*)d_in[11];
    const float* W2   = (const float*)d_in[12];
    const float* b2   = (const float*)d_in[13];
    const float* W3   = (const float*)d_in[14];
    const float* b3   = (const float*)d_in[15];
    const int* step_mask = (const int*)d_in[16];
    const int* ctx       = (const int*)d_in[17];
    unsigned short* hs = (unsigned short*)d_ws;  // 4*16384*128 f16-bits = 16.8 MB
    float* out = (float*)d_out;                  // f32, [2][4][16384] flat

    hipLaunchKernelGGL(gru_kernel, dim3(1), dim3(512), 0, stream,
                       px, py, vx, vy, Wemb, bemb, Wih, Whh, bih, bhh,
                       step_mask, ctx, hs);
    hipLaunchKernelGGL(head_kernel, dim3(1024), dim3(64), 0, stream,
                       W1, b1, W2, b2, W3, b3, (const __half*)hs, out);
}